// Round 14
// baseline (137.942 us; speedup 1.0000x reference)
//
#include <hip/hip_runtime.h>

// LPC synthesis (AR(15), frame-hopped coefs) + de-emphasis IIR.
//
// R20: BARRIER-FREE 2-TILE PIPELINE (single-wave blocks + reg prefetch).
// R12/R17/R19 all measured 41-42 us with ideal traffic: the time is the
// SERIAL phase sum (stage 6.6 + compute 17.5 + store 9.5 + slop) -- no
// overlap, because each block has one tile: a wave can't compute before
// its stage lands and does nothing after issuing its stores. Fixes that
// made this pipeline previously inexpressible are now both resolved:
//  - R13's reg-prefetch spill was the VGPR cap (84): __launch_bounds__
//    (64,3) raises the cap to ~170; prefetch holds 44 regs, est ~130.
//  - R15's store drain was __syncthreads' vmcnt(0): a SINGLE-WAVE block
//    needs no s_barrier at all -- every cross-lane LDS hazard is closed
//    by s_waitcnt lgkmcnt(0) (within-wave, cannot hang, never touches
//    vmcnt). There is NO vmcnt(0) anywhere in the loop: stores drain
//    under the next tile's compute; prefetch loads complete at their
//    register use (compiler-inserted precise waits).
// Per block: stage(t) -> issue loads(t+1) -> compute(t) -> store(t).
// Grid 55 x 64 = 3520 blocks at 13 blocks/CU (12 KB LDS) ~ 1.06
// generations: whole grid co-resident, each block self-overlapping.
// Numerics byte-identical to R19 (absmax 0.0078125): 48-sample AR
// warm-up (rho^48), fp32 staging + in-place fp32 z writeback (slot
// tid+2), 9-term Neumann de-emph init (r=0.97^40), pre-signal masking,
// odd/even tap select, fmaf(-a,..) neg folding, coalesced stage/store
// (R8/R16/R18: scattered global patterns leak to HBM; R9: LDS-coalesced
// store hits ideal WRITE at any occupancy).

namespace {
constexpr int kHS = 40;         // samples per half-frame
constexpr int kF = 3000;        // frames per batch
constexpr int kH = 2 * kF;      // 6000 half-frames per batch
constexpr int kL = kHS * kH;    // 240000
constexpr int kL4 = kL / 4;     // 60000 float4s per batch row
constexpr int kOrder = 16;
constexpr int kB = 64;
constexpr float kEmph = 0.97f;
constexpr int kThreads = 64;    // ONE wave per block -> no s_barrier
constexpr int kJunk = 9;        // 9-term correction needs 9 lead lanes
constexpr int kEmitH = kThreads - kJunk;  // 55 half-frames per tile
constexpr int kInSlots = kThreads + 2;    // 66 staged slots per tile
constexpr int kIn4 = kInSlots * 10;       // 660 staged float4s
constexpr int kTail = kIn4 - 10 * kThreads;  // 20 tail float4s
constexpr int kSlotW = 44;      // words per LDS slot (176 B, 16B-aligned)
constexpr int kNT = 2;          // tiles per block (pipeline depth)
constexpr int kCols = 55;       // 55*2 = 110 tiles covers 6000 half-frames
constexpr float kLg97 = -4.3943347e-2f;  // log2(0.97)
// powers of r = 0.97^40
constexpr float kR1 = 0.2957118f;
constexpr float kR2 = 0.08744547f;
constexpr float kR3 = 0.02585867f;
constexpr float kR4 = 0.00764671f;
constexpr float kR5 = 0.00226126f;
constexpr float kR6 = 6.6867e-4f;
constexpr float kR7 = 1.9773e-4f;
constexpr float kR8 = 5.8472e-5f;

typedef float vfloat4 __attribute__((ext_vector_type(4)));

// Within-wave LDS fence: all prior DS ops complete. Never waits vmcnt
// (prefetch loads + output stores stay in flight). sched_barrier(0)
// stops the scheduler hoisting dependent ops across (rule #18).
__device__ __forceinline__ void lds_fence() {
  __builtin_amdgcn_sched_barrier(0);
  asm volatile("s_waitcnt lgkmcnt(0)" ::: "memory");
  __builtin_amdgcn_sched_barrier(0);
}
}  // namespace

// One AR sample; 3 partial accumulators keep the cross-sample critical
// path at 1 fma + 1 add (8 cyc) vs ~38 cyc of issue. Taps consumed as
// -A[k] via the fmaf neg source modifier (zero cost).
#define AR_SAMPLE(A, s, e_in, ACC)                                         \
  float ACC;                                                               \
  {                                                                        \
    float t0 = (e_in);                                                     \
    t0 = fmaf(-A[14], x[((s)-15) & 15], t0);                               \
    t0 = fmaf(-A[13], x[((s)-14) & 15], t0);                               \
    t0 = fmaf(-A[12], x[((s)-13) & 15], t0);                               \
    t0 = fmaf(-A[11], x[((s)-12) & 15], t0);                               \
    t0 = fmaf(-A[10], x[((s)-11) & 15], t0);                               \
    float t1 = -A[9] * x[((s)-10) & 15];                                   \
    t1 = fmaf(-A[8], x[((s)-9) & 15], t1);                                 \
    t1 = fmaf(-A[7], x[((s)-8) & 15], t1);                                 \
    t1 = fmaf(-A[6], x[((s)-7) & 15], t1);                                 \
    t1 = fmaf(-A[5], x[((s)-6) & 15], t1);                                 \
    float t2 = -A[4] * x[((s)-5) & 15];                                    \
    t2 = fmaf(-A[3], x[((s)-4) & 15], t2);                                 \
    t2 = fmaf(-A[2], x[((s)-3) & 15], t2);                                 \
    t2 = fmaf(-A[1], x[((s)-2) & 15], t2);                                 \
    const float t01 = t0 + t1;               /* off critical path */       \
    t2 = fmaf(-A[0], x[((s)-1) & 15], t2);   /* critical: 1 fma */         \
    ACC = t01 + t2;                          /* + 1 add */                 \
    x[(s)&15] = ACC;                                                       \
  }

// Issue one tile's 11 coalesced excit loads into ex[] (lane-consecutive
// float4s -> full 1 KB bursts per wave; edge clamps are masked/unstored
// downstream). Registers only -- no LDS, no waits issued here.
#define LOAD_TILE(TILE)                                                    \
  {                                                                        \
    const int base4_ = ((TILE)*kEmitH - 11) * 10;                          \
    _Pragma("unroll") for (int p = 0; p < 11; ++p) {                       \
      const int i_ = min(tid + p * kThreads, kIn4 - 1);                    \
      const int g4_ = min(max(base4_ + i_, 0), kL4 - 1);                   \
      ex[p] = eg[g4_];                                                     \
    }                                                                      \
  }

__global__ __launch_bounds__(kThreads, 3) void lpc_synth_kernel(
    const float* __restrict__ excit, const float* __restrict__ coef,
    float* __restrict__ out) {
  __shared__ float s_x[kInSlots * kSlotW];  // 11616 B: input, then z
  __shared__ float s_zend[kThreads];        //   256 B: per-lane zh
  __shared__ float s_zp[kEmitH];            //   220 B: per-output Zp

  const int tid = threadIdx.x;
  const int b = blockIdx.y;
  const int tile0 = blockIdx.x * kNT;

  const float* __restrict__ ebase = excit + (size_t)b * kL;
  const float* __restrict__ cbase = coef + (size_t)b * kF * kOrder;
  const vfloat4* __restrict__ eg = (const vfloat4*)ebase;

  vfloat4 ex[11];  // prefetched excit tile (44 VGPRs, under the 170 cap)

  // ---- Prologue: fetch tile0 (exposed once per block).
  LOAD_TILE(tile0)

#pragma unroll
  for (int t = 0; t < kNT; ++t) {
    const int tile = tile0 + t;
    const int hbase = tile * kEmitH;
    const int ht = hbase + tid - kJunk;  // half-frame this lane emits
    const int hc = min(max(ht, 0), kH - 1);
    const int hw = min(max(ht - 2, 0), kH - 1);

    // ---- Stage ex -> LDS [slot][44] (frees ex for the next prefetch).
    // WAR vs store(t-1)'s ds_reads: same-wave DS program order + the
    // lds_fence at the end of the previous iteration.
#pragma unroll
    for (int p = 0; p < 11; ++p) {
      if (p < 10 || tid < kTail) {
        const int i = tid + p * kThreads;
        const int slot = i / 10;
        const int o = i - slot * 10;
        *(vfloat4*)(s_x + slot * kSlotW + o * 4) = ex[p];
      }
    }

    // ---- Tap loads (cache-hot, R12-measured), then NEXT tile's excit
    // prefetch: its ~900-cyc HBM latency hides under compute(t) below.
    const vfloat4* __restrict__ cp_ =
        (const vfloat4*)(cbase + (size_t)(hw >> 1) * kOrder);
    const vfloat4* __restrict__ cc_ =
        (const vfloat4*)(cbase + (size_t)(hc >> 1) * kOrder);
    const vfloat4 p0 = cp_[0], p1 = cp_[1], p2 = cp_[2], p3 = cp_[3];
    const vfloat4 q0 = cc_[0], q1 = cc_[1], q2 = cc_[2], q3 = cc_[3];
    if (t + 1 < kNT) LOAD_TILE(tile0 + t + 1)

    lds_fence();  // staging visible to cross-lane warm reads

    float pa_[15] = {p0.y, p0.z, p0.w, p1.x, p1.y, p1.z, p1.w, p2.x,
                     p2.y, p2.z, p2.w, p3.x, p3.y, p3.z, p3.w};
    const float ca_[15] = {q0.y, q0.z, q0.w, q1.x, q1.y, q1.z, q1.w, q2.x,
                           q2.y, q2.z, q2.w, q3.x, q3.y, q3.z, q3.w};

    // Ring buffer of last 16 y-samples; s = 0..87 (warm 0..47, emit
    // 48..87). Compile-time indexed -> VGPRs.
    float x[16];
#pragma unroll
    for (int i = 0; i < 16; ++i) x[i] = 0.f;

    // ---- Warm-up 48 samples from LDS (slots tid, tid+1).
    {
      const float* __restrict__ s2 = s_x + tid * kSlotW;        // ht-2
      const float* __restrict__ s1 = s_x + (tid + 1) * kSlotW;  // ht-1
      const float m2 = (ht >= 2) ? 1.f : 0.f;  // pre-signal inputs -> 0
      const float m1 = (ht >= 1) ? 1.f : 0.f;
      // Samples 0..7: tail (words 32..39) of half-frame ht-2, prev taps.
#pragma unroll
      for (int j = 8; j < 10; ++j) {
        const vfloat4 v = *(const vfloat4*)(s2 + 4 * j);
        const float f_[4] = {m2 * v.x, m2 * v.y, m2 * v.z, m2 * v.w};
#pragma unroll
        for (int q = 0; q < 4; ++q) {
          AR_SAMPLE(pa_, 4 * (j - 8) + q, f_[q], acc)
          (void)acc;
        }
      }
      // Half-frame ht-1 belongs to the emit frame when ht is odd:
      // one-time tap select (masked lanes don't care).
      if (ht & 1) {
#pragma unroll
        for (int k = 0; k < 15; ++k) pa_[k] = ca_[k];
      }
      // Samples 8..47: half-frame ht-1 in full.
#pragma unroll
      for (int j = 0; j < 10; ++j) {
        const vfloat4 v = *(const vfloat4*)(s1 + 4 * j);
        const float f_[4] = {m1 * v.x, m1 * v.y, m1 * v.z, m1 * v.w};
#pragma unroll
        for (int q = 0; q < 4; ++q) {
          AR_SAMPLE(pa_, 8 + 4 * j + q, f_[q], acc)
          (void)acc;
        }
      }
    }
    lds_fence();  // lane tid+2's warm reads of slot tid+2 done before WB

    // ---- Emit 40 samples: input from own slot (tid+2), z (fp32)
    // written back IN PLACE (read v before write; same-lane only).
    float z = 0.f;
    {
      float* __restrict__ so = s_x + (tid + 2) * kSlotW;
#pragma unroll
      for (int j = 0; j < 10; ++j) {
        const vfloat4 v = *(const vfloat4*)(so + 4 * j);
        vfloat4 zv;
#pragma unroll
        for (int q = 0; q < 4; ++q) {
          AR_SAMPLE(ca_, 48 + 4 * j + q, v[q], acc)
          z = fmaf(kEmph, z, acc);  // de-emph over this half-frame only
          if (q == 0) zv.x = z;
          if (q == 1) zv.y = z;
          if (q == 2) zv.z = z;
          if (q == 3) zv.w = z;
        }
        *(vfloat4*)(so + 4 * j) = zv;
      }
    }
    // zh = 0 outside the signal so correction terms vanish automatically.
    s_zend[tid] = (ht < 0 || ht >= kH) ? 0.f : z;
    lds_fence();  // writebacks + zend visible

    // ---- Per-output de-emph init (9-term Neumann, r = 0.97^40):
    // output k: Zp = sum_{i=1..9} r^(i-1) * zh[hbase+k-i].
    if (tid < kEmitH) {
      float Zp = s_zend[tid + 8];
      Zp = fmaf(kR1, s_zend[tid + 7], Zp);
      Zp = fmaf(kR2, s_zend[tid + 6], Zp);
      Zp = fmaf(kR3, s_zend[tid + 5], Zp);
      Zp = fmaf(kR4, s_zend[tid + 4], Zp);
      Zp = fmaf(kR5, s_zend[tid + 3], Zp);
      Zp = fmaf(kR6, s_zend[tid + 2], Zp);
      Zp = fmaf(kR7, s_zend[tid + 1], Zp);
      Zp = fmaf(kR8, s_zend[tid + 0], Zp);
      s_zp[tid] = Zp;
    }
    lds_fence();  // s_zp visible

    // ---- Coalesced store + correction: z += 0.97^(s+1) * Zp. Output k
    // lives in slot k+11. Lane-consecutive float4s -> full 1 KB bursts.
    // Fire-and-forget: no vmcnt wait exists in this loop; these drain
    // under the next tile's compute.
    {
      const int nv4 = min(kEmitH, kH - hbase) * 10;
      vfloat4* __restrict__ ob =
          (vfloat4*)(out + (size_t)b * kL + (size_t)hbase * kHS);
#pragma unroll 1
      for (int i = tid; i < nv4; i += kThreads) {
        const int k = i / 10;  // half-frame within tile
        const int j = i - 10 * k;
        const vfloat4 h =
            *(const vfloat4*)(s_x + (k + 11) * kSlotW + 4 * j);
        const float Zp = s_zp[k];
        const float ee = __builtin_exp2f(kLg97 * (float)(4 * j + 1));
        vfloat4 v;
        v.x = fmaf(ee, Zp, h.x);
        v.y = fmaf(ee * 0.97f, Zp, h.y);
        v.z = fmaf(ee * 0.9409f, Zp, h.z);
        v.w = fmaf(ee * 0.912673f, Zp, h.w);
        ob[i] = v;
      }
    }
    lds_fence();  // store-phase ds_reads done before next stage ds_writes
  }
}
#undef AR_SAMPLE
#undef LOAD_TILE

extern "C" void kernel_launch(void* const* d_in, const int* in_sizes, int n_in,
                              void* d_out, int out_size, void* d_ws,
                              size_t ws_size, hipStream_t stream) {
  const float* excit = (const float*)d_in[0];  // (B, L, 1) fp32
  const float* coef = (const float*)d_in[1];   // (B, F, 16) fp32
  float* out = (float*)d_out;                  // (B, L, 1) fp32

  dim3 grid(kCols, kB);  // 55 x 64 single-wave blocks, 2 tiles each
  lpc_synth_kernel<<<grid, kThreads, 0, stream>>>(excit, coef, out);
}

// Round 15
// 132.665 us; speedup vs baseline: 1.0398x; 1.0398x over previous
//
#include <hip/hip_runtime.h>

// LPC synthesis (AR(15), frame-hopped coefs) + de-emphasis IIR.
//
// R21: ZERO-REGISTER DMA PIPELINE, SINGLE-WAVE, COUNTED VMCNT.
// Combines the two proven-separately pieces while avoiding every failure
// mode measured this session:
//  - global_load_lds staging (R15: ran+passed) holds ZERO registers ->
//    immune to the reg-prefetch spill that killed R13 (FETCH/WRITE +25MB
//    symmetric) and R20 (VGPR capped at 84, ex[11] spilled, WRITE +15MB).
//  - single-wave blocks (R19/R20): no s_barrier ANYWHERE -> no hang mode
//    (R14's risk); cross-lane LDS hazards closed by s_waitcnt lgkmcnt(0),
//    which never touches vmcnt.
//  - counted vmcnt: vmcnt accounting is IN-ORDER, so tile t's stores can
//    only stay in flight across the tile-(t+1) wait if ALL tile-(t+1)
//    loads are issued BEFORE the stores. Per-iteration issue order:
//      [wait vmcnt(9)] -> taps(t+1) 8 loads -> DMA(t+1) 12 ops
//      -> compute(t) -> stores(t) 9 ops
//    The wait forces {taps,DMA}(t) retired (older) while allowing the 9
//    newest (stores t-1) outstanding. t=0 uses vmcnt(0) (nothing older).
//    9 = ceil(550 float4s / 64 lanes) store instructions per tile.
//  - taps(t+1) held in 32 VGPRs only; __launch_bounds__(64,1) leaves the
//    allocator free (R20 lesson: never constrain occupancy with live
//    prefetch state).
// LDS: 2 buffers x 12 chunks x 1KB (66 slots x 44 floats + pad; DMA
// writes are wave-linear so buffers are padded to the 12-chunk boundary
// to keep the tail ops inside the buffer) + zend + zp ~ 25 KB -> 6
// blocks/CU; grid 22x64 = 1408 blocks = 5.5/CU, all co-resident, kNT=5
// tiles each. Numerics byte-identical to R19 (absmax 0.0078125):
// 48-sample AR warm-up (rho^48), fp32 everywhere, in-place z writeback
// (slot tid+2), 9-term Neumann de-emph init (r=0.97^40), pre-signal
// masking, odd/even tap select, fmaf(-a,..) neg folding, coalesced
// store phase (R8/R9).

namespace {
constexpr int kHS = 40;         // samples per half-frame
constexpr int kF = 3000;        // frames per batch
constexpr int kH = 2 * kF;      // 6000 half-frames per batch
constexpr int kL = kHS * kH;    // 240000
constexpr int kOrder = 16;
constexpr int kB = 64;
constexpr float kEmph = 0.97f;
constexpr int kThreads = 64;    // ONE wave per block -> no s_barrier
constexpr int kJunk = 9;        // 9-term correction needs 9 lead lanes
constexpr int kEmitH = kThreads - kJunk;  // 55 half-frames per tile
constexpr int kInSlots = 66;    // staged slots: hbase-11 .. hbase+54
constexpr int kSlotW = 44;      // floats per slot (176 B; 11 float4s)
constexpr int kChunks = 12;     // DMA 1KB chunks: ceil(66*11/64)
constexpr int kBufF = kChunks * 256;  // 3072 floats (padded buffer)
constexpr int kNT = 5;          // tiles per block
constexpr int kCols = 22;       // 22*5 = 110 tiles = ceil(6000/55)
constexpr float kLg97 = -4.3943347e-2f;  // log2(0.97)
// powers of r = 0.97^40
constexpr float kR1 = 0.2957118f;
constexpr float kR2 = 0.08744547f;
constexpr float kR3 = 0.02585867f;
constexpr float kR4 = 0.00764671f;
constexpr float kR5 = 0.00226126f;
constexpr float kR6 = 6.6867e-4f;
constexpr float kR7 = 1.9773e-4f;
constexpr float kR8 = 5.8472e-5f;

typedef float vfloat4 __attribute__((ext_vector_type(4)));

// Within-wave LDS fence (never waits vmcnt; rule #18 sched fences).
__device__ __forceinline__ void lds_fence() {
  __builtin_amdgcn_sched_barrier(0);
  asm volatile("s_waitcnt lgkmcnt(0)" ::: "memory");
  __builtin_amdgcn_sched_barrier(0);
}

// Issue the 12 DMA ops staging one tile (zero VGPRs held). LDS image:
// [slot][44 floats], slot s <-> half-frame hbase + s - 11 (+1 overlap
// float4 per slot, real data). LDS dest = wave-uniform chunk base +
// lane*16 (HW semantics); per-lane GLOBAL address realizes the layout.
__device__ __forceinline__ void stage_tile(const float* __restrict__ ebase,
                                           float* sbuf, int hbase, int ln) {
#pragma unroll
  for (int c = 0; c < kChunks; ++c) {
    const int W4 = c * 64 + ln;               // flat float4 index
    const int s = min(W4 / 11, kInSlots - 1); // slot (tail clamps)
    const int o4 = W4 - s * 11;               // float4 within slot
    const int hts = hbase + s - 11;
    const int hcs = min(max(hts, 0), kH - 1);
    const int fidx = min(hcs * kHS + o4 * 4, kL - 4);
    __builtin_amdgcn_global_load_lds(
        (const __attribute__((address_space(1))) float*)(ebase + fidx),
        (__attribute__((address_space(3))) float*)(sbuf + (c << 8)), 16, 0,
        0);
  }
}
}  // namespace

// One AR sample; 3 partial accumulators keep the cross-sample critical
// path at 1 fma + 1 add (8 cyc). Taps consumed as -A[k] via the fmaf
// neg source modifier (zero cost).
#define AR_SAMPLE(A, s, e_in, ACC)                                         \
  float ACC;                                                               \
  {                                                                        \
    float t0 = (e_in);                                                     \
    t0 = fmaf(-A[14], x[((s)-15) & 15], t0);                               \
    t0 = fmaf(-A[13], x[((s)-14) & 15], t0);                               \
    t0 = fmaf(-A[12], x[((s)-13) & 15], t0);                               \
    t0 = fmaf(-A[11], x[((s)-12) & 15], t0);                               \
    t0 = fmaf(-A[10], x[((s)-11) & 15], t0);                               \
    float t1 = -A[9] * x[((s)-10) & 15];                                   \
    t1 = fmaf(-A[8], x[((s)-9) & 15], t1);                                 \
    t1 = fmaf(-A[7], x[((s)-8) & 15], t1);                                 \
    t1 = fmaf(-A[6], x[((s)-7) & 15], t1);                                 \
    t1 = fmaf(-A[5], x[((s)-6) & 15], t1);                                 \
    float t2 = -A[4] * x[((s)-5) & 15];                                    \
    t2 = fmaf(-A[3], x[((s)-4) & 15], t2);                                 \
    t2 = fmaf(-A[2], x[((s)-3) & 15], t2);                                 \
    t2 = fmaf(-A[1], x[((s)-2) & 15], t2);                                 \
    const float t01 = t0 + t1;               /* off critical path */       \
    t2 = fmaf(-A[0], x[((s)-1) & 15], t2);   /* critical: 1 fma */         \
    ACC = t01 + t2;                          /* + 1 add */                 \
    x[(s)&15] = ACC;                                                       \
  }

__global__ __launch_bounds__(kThreads, 1) void lpc_synth_kernel(
    const float* __restrict__ excit, const float* __restrict__ coef,
    float* __restrict__ out) {
  __shared__ float s_ex[2 * kBufF];   // 24576 B: double-buffered tiles
  __shared__ float s_zend[kThreads];  //   256 B: per-lane zh
  __shared__ float s_zp[kEmitH];      //   220 B: per-output Zp

  const int tid = threadIdx.x;  // == lane (single wave)
  const int b = blockIdx.y;
  const int tile0 = blockIdx.x * kNT;

  const float* __restrict__ ebase = excit + (size_t)b * kL;
  const float* __restrict__ cbase = coef + (size_t)b * kF * kOrder;

  // Current-tile taps (rotated from the prefetch each iteration).
  vfloat4 p0, p1, p2, p3, q0, q1, q2, q3;
  // Next-tile tap prefetch (32 VGPRs held across one compute phase).
  vfloat4 n0, n1, n2, n3, m0, m1v, m2v, m3;

  // ---- Prologue: taps(tile0) + DMA(tile0). Issue order: taps first.
  {
    const int ht = tile0 * kEmitH + tid - kJunk;
    const int hc = min(max(ht, 0), kH - 1);
    const int hw = min(max(ht - 2, 0), kH - 1);
    const vfloat4* __restrict__ cp_ =
        (const vfloat4*)(cbase + (size_t)(hw >> 1) * kOrder);
    const vfloat4* __restrict__ cc_ =
        (const vfloat4*)(cbase + (size_t)(hc >> 1) * kOrder);
    p0 = cp_[0]; p1 = cp_[1]; p2 = cp_[2]; p3 = cp_[3];
    q0 = cc_[0]; q1 = cc_[1]; q2 = cc_[2]; q3 = cc_[3];
    stage_tile(ebase, s_ex, tile0 * kEmitH, tid);
  }

#pragma unroll 1
  for (int t = 0; t < kNT; ++t) {
    const int tile = tile0 + t;
    const int hbase = tile * kEmitH;
    const int ht = hbase + tid - kJunk;  // half-frame this lane emits
    float* __restrict__ sb = s_ex + (t & 1) * kBufF;

    // ---- Counted wait: {taps,DMA}(t) are the oldest outstanding vmem
    // ops; stores(t-1) (9, the newest) may stay in flight. In-order
    // accounting makes vmcnt(9) force exactly the older group. t=0 has
    // no stores -> vmcnt(0). No s_barrier exists: cannot hang.
    __builtin_amdgcn_sched_barrier(0);
    if (t == 0) {
      asm volatile("s_waitcnt vmcnt(0)" ::: "memory");
    } else {
      asm volatile("s_waitcnt vmcnt(9)" ::: "memory");
    }
    __builtin_amdgcn_sched_barrier(0);

    // ---- Issue ALL tile-(t+1) loads now, BEFORE compute and stores:
    // taps -> registers (8 ops), excit -> other LDS buffer (12 DMA ops).
    // Their latency hides under compute(t) (~3500 cyc >> ~900 cyc HBM).
    if (t + 1 < kNT) {
      const int htn = (tile + 1) * kEmitH + tid - kJunk;
      const int hcn = min(max(htn, 0), kH - 1);
      const int hwn = min(max(htn - 2, 0), kH - 1);
      const vfloat4* __restrict__ cpn =
          (const vfloat4*)(cbase + (size_t)(hwn >> 1) * kOrder);
      const vfloat4* __restrict__ ccn =
          (const vfloat4*)(cbase + (size_t)(hcn >> 1) * kOrder);
      n0 = cpn[0]; n1 = cpn[1]; n2 = cpn[2]; n3 = cpn[3];
      m0 = ccn[0]; m1v = ccn[1]; m2v = ccn[2]; m3 = ccn[3];
      stage_tile(ebase, s_ex + ((t + 1) & 1) * kBufF,
                 (tile + 1) * kEmitH, tid);
    }
    __builtin_amdgcn_sched_barrier(0);

    // ---- Compute(t). Taps already in registers (waited above).
    float pa_[15] = {p0.y, p0.z, p0.w, p1.x, p1.y, p1.z, p1.w, p2.x,
                     p2.y, p2.z, p2.w, p3.x, p3.y, p3.z, p3.w};
    const float ca_[15] = {q0.y, q0.z, q0.w, q1.x, q1.y, q1.z, q1.w, q2.x,
                           q2.y, q2.z, q2.w, q3.x, q3.y, q3.z, q3.w};

    float x[16];
#pragma unroll
    for (int i = 0; i < 16; ++i) x[i] = 0.f;

    // Warm-up 48 samples from LDS (slots tid, tid+1 of this buffer).
    {
      const float* __restrict__ s2 = sb + tid * kSlotW;        // ht-2
      const float* __restrict__ s1 = sb + (tid + 1) * kSlotW;  // ht-1
      const float mm2 = (ht >= 2) ? 1.f : 0.f;  // pre-signal -> 0
      const float mm1 = (ht >= 1) ? 1.f : 0.f;
      // Samples 0..7: tail (words 32..39) of half-frame ht-2, prev taps.
#pragma unroll
      for (int j = 8; j < 10; ++j) {
        const vfloat4 v = *(const vfloat4*)(s2 + 4 * j);
        const float f_[4] = {mm2 * v.x, mm2 * v.y, mm2 * v.z, mm2 * v.w};
#pragma unroll
        for (int q = 0; q < 4; ++q) {
          AR_SAMPLE(pa_, 4 * (j - 8) + q, f_[q], acc)
          (void)acc;
        }
      }
      // Half-frame ht-1 uses emit-frame taps when ht is odd.
      if (ht & 1) {
#pragma unroll
        for (int k = 0; k < 15; ++k) pa_[k] = ca_[k];
      }
      // Samples 8..47: half-frame ht-1 in full.
#pragma unroll
      for (int j = 0; j < 10; ++j) {
        const vfloat4 v = *(const vfloat4*)(s1 + 4 * j);
        const float f_[4] = {mm1 * v.x, mm1 * v.y, mm1 * v.z, mm1 * v.w};
#pragma unroll
        for (int q = 0; q < 4; ++q) {
          AR_SAMPLE(pa_, 8 + 4 * j + q, f_[q], acc)
          (void)acc;
        }
      }
    }
    lds_fence();  // same-wave order safety before in-place writes

    // Emit 40 samples: input from own slot (tid+2), fp32 z written back
    // IN PLACE (read v before write; same-lane only).
    float z = 0.f;
    {
      float* __restrict__ so = sb + (tid + 2) * kSlotW;
#pragma unroll
      for (int j = 0; j < 10; ++j) {
        const vfloat4 v = *(const vfloat4*)(so + 4 * j);
        vfloat4 zv;
#pragma unroll
        for (int q = 0; q < 4; ++q) {
          AR_SAMPLE(ca_, 48 + 4 * j + q, v[q], acc)
          z = fmaf(kEmph, z, acc);
          if (q == 0) zv.x = z;
          if (q == 1) zv.y = z;
          if (q == 2) zv.z = z;
          if (q == 3) zv.w = z;
        }
        *(vfloat4*)(so + 4 * j) = zv;
      }
    }
    s_zend[tid] = (ht < 0 || ht >= kH) ? 0.f : z;
    lds_fence();  // writebacks + zend visible

    // Per-output de-emph init (9-term Neumann, r = 0.97^40).
    if (tid < kEmitH) {
      float Zp = s_zend[tid + 8];
      Zp = fmaf(kR1, s_zend[tid + 7], Zp);
      Zp = fmaf(kR2, s_zend[tid + 6], Zp);
      Zp = fmaf(kR3, s_zend[tid + 5], Zp);
      Zp = fmaf(kR4, s_zend[tid + 4], Zp);
      Zp = fmaf(kR5, s_zend[tid + 3], Zp);
      Zp = fmaf(kR6, s_zend[tid + 2], Zp);
      Zp = fmaf(kR7, s_zend[tid + 1], Zp);
      Zp = fmaf(kR8, s_zend[tid + 0], Zp);
      s_zp[tid] = Zp;
    }
    lds_fence();  // s_zp visible

    // ---- Coalesced store + correction (9 store instructions = the
    // vmcnt(9) budget). Fire-and-forget: nothing in this loop ever
    // waits them; they drain under compute(t+1).
    {
      const int nv4 = min(kEmitH, kH - hbase) * 10;
      vfloat4* __restrict__ ob =
          (vfloat4*)(out + (size_t)b * kL + (size_t)hbase * kHS);
#pragma unroll 1
      for (int i = tid; i < nv4; i += kThreads) {
        const int k = i / 10;  // half-frame within tile -> slot k+11
        const int j = i - 10 * k;
        const vfloat4 h = *(const vfloat4*)(sb + (k + 11) * kSlotW + 4 * j);
        const float Zp = s_zp[k];
        const float ee = __builtin_exp2f(kLg97 * (float)(4 * j + 1));
        vfloat4 v;
        v.x = fmaf(ee, Zp, h.x);
        v.y = fmaf(ee * 0.97f, Zp, h.y);
        v.z = fmaf(ee * 0.9409f, Zp, h.z);
        v.w = fmaf(ee * 0.912673f, Zp, h.w);
        ob[i] = v;
      }
    }
    lds_fence();  // store-phase ds_reads done before next stage's writes

    // ---- Rotate tap prefetch into current.
    if (t + 1 < kNT) {
      p0 = n0; p1 = n1; p2 = n2; p3 = n3;
      q0 = m0; q1 = m1v; q2 = m2v; q3 = m3;
    }
  }
}
#undef AR_SAMPLE

extern "C" void kernel_launch(void* const* d_in, const int* in_sizes, int n_in,
                              void* d_out, int out_size, void* d_ws,
                              size_t ws_size, hipStream_t stream) {
  const float* excit = (const float*)d_in[0];  // (B, L, 1) fp32
  const float* coef = (const float*)d_in[1];   // (B, F, 16) fp32
  float* out = (float*)d_out;                  // (B, L, 1) fp32

  dim3 grid(kCols, kB);  // 22 x 64 single-wave blocks, 5 tiles each
  lpc_synth_kernel<<<grid, kThreads, 0, stream>>>(excit, coef, out);
}